// Round 19
// baseline (127.889 us; speedup 1.0000x reference)
//
#include <hip/hip_runtime.h>
#include <stdint.h>

#define C_IN 256
#define HW   56
#define HW2  3136          // 56*56
#define SPAN 2304          // 9*256
#define TS   16
#define BKT  32

typedef __attribute__((ext_vector_type(8)))  short short8;
typedef __attribute__((ext_vector_type(4)))  float f32x4;
typedef __attribute__((ext_vector_type(16))) float f32x16;
typedef float f32x4u __attribute__((ext_vector_type(4), aligned(4)));   // 4B-aligned vector load

// d_ws layout: [0..127]: rows (32 x int32). [512 ...]: Wpack ushort[73728]

// ---------------------------------------------------------------------------
// Kernel 1: hash -> 32 gathered row ids (byte-identical to all PASS rounds).
// ---------------------------------------------------------------------------
__global__ void hash_rows_kernel(const float* __restrict__ x,
                                 const float* __restrict__ a,
                                 const int*   __restrict__ table,
                                 int*         __restrict__ rows_out) {
    __shared__ float rd[256];
    __shared__ float rn[256];
    const int t = threadIdx.x;
    float dv = 0.f, nq = 0.f;
    for (int k = t; k < SPAN; k += 256) {
        const int p = k >> 8;
        const int c = k & 255;
        const int i = p / 3, j = p % 3;
        float v = 0.f;
        if (i >= 1 && j >= 1) v = x[c * HW2 + (i - 1) * HW + (j - 1)];
        dv += a[k] * v;
        nq += v * v;
    }
    rd[t] = dv; rn[t] = nq;
    __syncthreads();
    for (int s = 128; s > 0; s >>= 1) {
        if (t < s) { rd[t] += rd[t + s]; rn[t] += rn[t + s]; }
        __syncthreads();
    }
    if (t == 0) {
        const float nrm = sqrtf(rn[0]);
        const float sv  = rd[0] / nrm
                        + 0.5f * (a[SPAN] + a[SPAN+1] + a[SPAN+2] + a[SPAN+3] + a[SPAN+4]);
        const int idx = ((int)fabsf(floorf(sv))) % TS;
        #pragma unroll
        for (int b = 0; b < BKT; ++b) rows_out[b] = table[idx * BKT + b];
    }
}

// ---------------------------------------------------------------------------
// Kernel 2: build Wpack for 32x32x16 A-fragments (byte-identical to rounds
// 12-16 PASS). Chunk Q = ccb*18 + p*2 + ch16 (144 chunks of K=16).
// Lane l elem j: A[brow = l&31][k = p*256 + ccb*32 + ch16*16 + (l>>5)*8 + j].
// ---------------------------------------------------------------------------
__global__ void build_wpack_kernel(const float* __restrict__ kernels,
                                   const int*   __restrict__ rows,
                                   unsigned short* __restrict__ wp) {
    const int idx   = blockIdx.x * 256 + threadIdx.x;   // 0..73727
    const int j     = idx & 7;
    const int l     = (idx >> 3) & 63;
    const int Q     = idx >> 9;          // 0..143
    const int ccb   = Q / 18;
    const int rem   = Q % 18;
    const int p     = rem >> 1;
    const int ch16  = rem & 1;
    const int brow  = l & 31;
    const int khalf = l >> 5;
    const int k     = p * 256 + ccb * 32 + ch16 * 16 + khalf * 8 + j;
    const int row   = rows[brow];
    const float v = kernels[(size_t)row * SPAN + k] * 16.0f;
    unsigned u = __builtin_bit_cast(unsigned, v);
    u = (u + 0x7fffu + ((u >> 16) & 1u)) >> 16;       // RNE fp32->bf16
    wp[idx] = (unsigned short)u;
}

// ---------------------------------------------------------------------------
// Kernel 3: implicit-GEMM via mfma_f32_32x32x16_bf16 — r14/r16 PASS inner
// body verbatim, re-tiled for SINGLE-GENERATION residency:
//   block = 256 threads = 4 waves, one 32-col tile; wave runs 2 ccb
//   sequentially (ccb = wid*2+cq, r6-proven accumulation).
//   GRID = 1568 tiles (r18 bug: launched 3136 -> n OOB -> memory fault).
//   1568 = 6.125 blocks/CU with an 8-block residency cap (VGPR<=64 bucket,
//   2048-thread cap, 8KB LDS) -> ALL blocks resident in one generation,
//   no 2nd-generation tail (r14's 4-block cap forced 2 generations = the
//   measured 34% occupancy).
//   In-block reduce: 4 partials, r16 two-phase idiom, 2 regions x 4KB LDS.
// ---------------------------------------------------------------------------
__global__ __launch_bounds__(256, 8)
void alsh_mfma_kernel(const float* __restrict__ x,
                      const unsigned short* __restrict__ wp,
                      float* __restrict__ out) {
    __shared__ float red[2 * 1024];             // 8KB: 2 regions x (32 b0 x 32 col)

    const int b  = blockIdx.x;                  // 0..1567
    const int ct = (b & 7) * 196 + (b >> 3);    // XCD chunk swizzle (1568 = 8*196)

    const int t     = threadIdx.x;              // 0..255
    const int lane  = t & 63;
    const int wid   = t >> 6;                   // 0..3
    const int col   = lane & 31;                // B-col / D-col
    const int khalf = lane >> 5;                // k-half 0..1
    const int s0    = ct * 32;                  // block's base column (0..50144)
    const int n     = s0 / HW2;                 // block-uniform (3136 = 98*32)
    const int s0img = s0 - n * HW2;
    const int sl    = s0img + col;              // lane's spatial idx in image
    const int h     = sl / HW;
    const int w     = sl - h * HW;
    const float* xn = x + (size_t)n * (C_IN * HW2);
    const short8* wpv = (const short8*)wp;

    f32x16 acc = {0.f,0.f,0.f,0.f, 0.f,0.f,0.f,0.f, 0.f,0.f,0.f,0.f, 0.f,0.f,0.f,0.f};

    #pragma unroll
    for (int cq = 0; cq < 2; ++cq) {            // 2 ccb per wave (r6-proven)
        const int ccb = wid * 2 + cq;
        const int cc  = ccb * 32;
        #pragma unroll
        for (int dd = 0; dd < 3; ++dd) {        // di = dd-1
            const int di     = dd - 1;
            const int rowpos = sl + di * HW;    // pos at dj=0
            const int posm   = rowpos - 1;      // window base (dj=-1)
            const int pc     = posm < 0 ? 0 : (posm > HW2 - 4 ? HW2 - 4 : posm);
            const bool shifted = (pc != posm);  // edge lanes only
            const int ih = h + di;

            #pragma unroll
            for (int ch16 = 0; ch16 < 2; ++ch16) {
                f32x4 V[8];
                #pragma unroll
                for (int j = 0; j < 8; ++j) {
                    const int ch = cc + ch16 * 16 + khalf * 8 + j;
                    V[j] = *(const f32x4u*)(xn + (size_t)ch * HW2 + pc);
                }

                #pragma unroll
                for (int dd2 = 0; dd2 < 3; ++dd2) { // dj = dd2-1
                    const int dj = dd2 - 1;
                    const int iw = w + dj;
                    const bool ok = ((unsigned)ih < (unsigned)HW) & ((unsigned)iw < (unsigned)HW);
                    const int voff = rowpos + dj;

                    short8 bf;
                    #pragma unroll
                    for (int j = 0; j < 8; ++j) {
                        float v = V[j][dd2];    // = x[ch][voff] when !shifted
                        if (shifted) {          // exec-masked scalar fallback
                            const int vc = voff < 0 ? 0 : (voff > HW2 - 1 ? HW2 - 1 : voff);
                            v = xn[(size_t)(cc + ch16 * 16 + khalf * 8 + j) * HW2 + vc];
                        }
                        v = ok ? v : 0.f;
                        const unsigned u = __builtin_bit_cast(unsigned, v);
                        bf[j] = (short)((u + 0x8000u) >> 16);   // fp32->bf16 round
                    }

                    const int Q = ccb * 18 + (dd * 3 + dd2) * 2 + ch16;
                    const short8 a = wpv[Q * 64 + lane];
                    acc = __builtin_amdgcn_mfma_f32_32x32x16_bf16(a, bf, acc, 0, 0, 0);
                }
            }
        }
    }

    // ---- in-block K-reduce, two-phase (r16 PASS idiom), 4 partials ----
    // C/D: col = lane&31, row b0 = (reg&3) + 8*(reg>>2) + 4*khalf (r12-proven)
    const int base = (wid & 1) * 1024;
    if (wid < 2) {
        #pragma unroll
        for (int i2 = 0; i2 < 16; ++i2) {
            const int b0 = (i2 & 3) + 8 * (i2 >> 2) + 4 * khalf;
            red[base + b0 * 32 + col] = acc[i2];
        }
    }
    __syncthreads();
    if (wid >= 2) {
        #pragma unroll
        for (int i2 = 0; i2 < 16; ++i2) {
            const int b0 = (i2 & 3) + 8 * (i2 >> 2) + 4 * khalf;
            red[base + b0 * 32 + col] += acc[i2];
        }
    }
    __syncthreads();

    float* on = out + (size_t)n * (BKT * HW2) + s0img;
    #pragma unroll
    for (int e = 0; e < 4; ++e) {
        const int elem = e * 256 + t;           // 0..1023 = b0*32 + c
        const float s = red[elem] + red[1024 + elem];
        on[(size_t)(elem >> 5) * HW2 + (elem & 31)] = s;
    }
}

// ---------------------------------------------------------------------------
extern "C" void kernel_launch(void* const* d_in, const int* in_sizes, int n_in,
                              void* d_out, int out_size, void* d_ws, size_t ws_size,
                              hipStream_t stream) {
    const float* x       = (const float*)d_in[0];
    const float* kernels = (const float*)d_in[1];
    const float* a       = (const float*)d_in[2];
    const int*   table   = (const int*)d_in[3];
    float* out = (float*)d_out;
    int*   rows = (int*)d_ws;
    unsigned short* wpack = (unsigned short*)((char*)d_ws + 512);

    hipLaunchKernelGGL(hash_rows_kernel, dim3(1), dim3(256), 0, stream,
                       x, a, table, rows);
    hipLaunchKernelGGL(build_wpack_kernel, dim3(288), dim3(256), 0, stream,
                       kernels, rows, wpack);
    hipLaunchKernelGGL(alsh_mfma_kernel, dim3(1568), dim3(256), 0, stream,
                       x, wpack, out);
}

// Round 20
// 66.030 us; speedup vs baseline: 1.9368x; 1.9368x over previous
//
#include <hip/hip_runtime.h>
#include <stdint.h>

#define C_IN 256
#define HW   56
#define HW2  3136          // 56*56
#define SPAN 2304          // 9*256
#define TS   16
#define BKT  32

typedef __attribute__((ext_vector_type(8)))  short short8;
typedef __attribute__((ext_vector_type(4)))  float f32x4;
typedef __attribute__((ext_vector_type(16))) float f32x16;
typedef float f32x4u __attribute__((ext_vector_type(4), aligned(4)));   // 4B-aligned vector load

// d_ws layout: [0..127]: rows (32 x int32). [512 ...]: Wpack ushort[73728]

// ---------------------------------------------------------------------------
// Kernel 1: hash -> 32 gathered row ids (byte-identical to all PASS rounds).
// ---------------------------------------------------------------------------
__global__ void hash_rows_kernel(const float* __restrict__ x,
                                 const float* __restrict__ a,
                                 const int*   __restrict__ table,
                                 int*         __restrict__ rows_out) {
    __shared__ float rd[256];
    __shared__ float rn[256];
    const int t = threadIdx.x;
    float dv = 0.f, nq = 0.f;
    for (int k = t; k < SPAN; k += 256) {
        const int p = k >> 8;
        const int c = k & 255;
        const int i = p / 3, j = p % 3;
        float v = 0.f;
        if (i >= 1 && j >= 1) v = x[c * HW2 + (i - 1) * HW + (j - 1)];
        dv += a[k] * v;
        nq += v * v;
    }
    rd[t] = dv; rn[t] = nq;
    __syncthreads();
    for (int s = 128; s > 0; s >>= 1) {
        if (t < s) { rd[t] += rd[t + s]; rn[t] += rn[t + s]; }
        __syncthreads();
    }
    if (t == 0) {
        const float nrm = sqrtf(rn[0]);
        const float sv  = rd[0] / nrm
                        + 0.5f * (a[SPAN] + a[SPAN+1] + a[SPAN+2] + a[SPAN+3] + a[SPAN+4]);
        const int idx = ((int)fabsf(floorf(sv))) % TS;
        #pragma unroll
        for (int b = 0; b < BKT; ++b) rows_out[b] = table[idx * BKT + b];
    }
}

// ---------------------------------------------------------------------------
// Kernel 2: build Wpack for 32x32x16 A-fragments (byte-identical to rounds
// 12-16 PASS). Chunk Q = ccb*18 + p*2 + ch16 (144 chunks of K=16).
// Lane l elem j: A[brow = l&31][k = p*256 + ccb*32 + ch16*16 + (l>>5)*8 + j].
// ---------------------------------------------------------------------------
__global__ void build_wpack_kernel(const float* __restrict__ kernels,
                                   const int*   __restrict__ rows,
                                   unsigned short* __restrict__ wp) {
    const int idx   = blockIdx.x * 256 + threadIdx.x;   // 0..73727
    const int j     = idx & 7;
    const int l     = (idx >> 3) & 63;
    const int Q     = idx >> 9;          // 0..143
    const int ccb   = Q / 18;
    const int rem   = Q % 18;
    const int p     = rem >> 1;
    const int ch16  = rem & 1;
    const int brow  = l & 31;
    const int khalf = l >> 5;
    const int k     = p * 256 + ccb * 32 + ch16 * 16 + khalf * 8 + j;
    const int row   = rows[brow];
    const float v = kernels[(size_t)row * SPAN + k] * 16.0f;
    unsigned u = __builtin_bit_cast(unsigned, v);
    u = (u + 0x7fffu + ((u >> 16) & 1u)) >> 16;       // RNE fp32->bf16
    wp[idx] = (unsigned short)u;
}

// ---------------------------------------------------------------------------
// Kernel 3: implicit-GEMM via mfma_f32_32x32x16_bf16 — r14/r16 PASS inner
// body verbatim, re-tiled for SINGLE-GENERATION residency:
//   block = 256 threads = 4 waves, one 32-col tile; wave runs 2 ccb
//   sequentially (ccb = wid*2+cq, r6-proven accumulation). Grid 1568.
//   launch_bounds(256,4): VGPR budget 128 (r14's proven setting for this
//   body -> ~52-60 alloc, NO spill). r19's (256,8) forced a 64-reg cap and
//   spilled (FETCH/WRITE 147/157MB, 151us). With ~52 VGPR the HW can still
//   run 8 waves/SIMD -> 8 blocks/CU -> all 6.125 blocks/CU resident in ONE
//   generation (r14's 512-thread blocks hit the 4-block thread cap -> 2
//   generations = the measured 34% occupancy).
//   In-block reduce: 4 partials, r16 two-phase idiom, 2 regions x 4KB LDS.
// ---------------------------------------------------------------------------
__global__ __launch_bounds__(256, 4)
void alsh_mfma_kernel(const float* __restrict__ x,
                      const unsigned short* __restrict__ wp,
                      float* __restrict__ out) {
    __shared__ float red[2 * 1024];             // 8KB: 2 regions x (32 b0 x 32 col)

    const int b  = blockIdx.x;                  // 0..1567
    const int ct = (b & 7) * 196 + (b >> 3);    // XCD chunk swizzle (1568 = 8*196)

    const int t     = threadIdx.x;              // 0..255
    const int lane  = t & 63;
    const int wid   = t >> 6;                   // 0..3
    const int col   = lane & 31;                // B-col / D-col
    const int khalf = lane >> 5;                // k-half 0..1
    const int s0    = ct * 32;                  // block's base column (0..50144)
    const int n     = s0 / HW2;                 // block-uniform (3136 = 98*32)
    const int s0img = s0 - n * HW2;
    const int sl    = s0img + col;              // lane's spatial idx in image
    const int h     = sl / HW;
    const int w     = sl - h * HW;
    const float* xn = x + (size_t)n * (C_IN * HW2);
    const short8* wpv = (const short8*)wp;

    f32x16 acc = {0.f,0.f,0.f,0.f, 0.f,0.f,0.f,0.f, 0.f,0.f,0.f,0.f, 0.f,0.f,0.f,0.f};

    #pragma unroll
    for (int cq = 0; cq < 2; ++cq) {            // 2 ccb per wave (r6-proven)
        const int ccb = wid * 2 + cq;
        const int cc  = ccb * 32;
        #pragma unroll
        for (int dd = 0; dd < 3; ++dd) {        // di = dd-1
            const int di     = dd - 1;
            const int rowpos = sl + di * HW;    // pos at dj=0
            const int posm   = rowpos - 1;      // window base (dj=-1)
            const int pc     = posm < 0 ? 0 : (posm > HW2 - 4 ? HW2 - 4 : posm);
            const bool shifted = (pc != posm);  // edge lanes only
            const int ih = h + di;

            #pragma unroll
            for (int ch16 = 0; ch16 < 2; ++ch16) {
                f32x4 V[8];
                #pragma unroll
                for (int j = 0; j < 8; ++j) {
                    const int ch = cc + ch16 * 16 + khalf * 8 + j;
                    V[j] = *(const f32x4u*)(xn + (size_t)ch * HW2 + pc);
                }

                #pragma unroll
                for (int dd2 = 0; dd2 < 3; ++dd2) { // dj = dd2-1
                    const int dj = dd2 - 1;
                    const int iw = w + dj;
                    const bool ok = ((unsigned)ih < (unsigned)HW) & ((unsigned)iw < (unsigned)HW);
                    const int voff = rowpos + dj;

                    short8 bf;
                    #pragma unroll
                    for (int j = 0; j < 8; ++j) {
                        float v = V[j][dd2];    // = x[ch][voff] when !shifted
                        if (shifted) {          // exec-masked scalar fallback
                            const int vc = voff < 0 ? 0 : (voff > HW2 - 1 ? HW2 - 1 : voff);
                            v = xn[(size_t)(cc + ch16 * 16 + khalf * 8 + j) * HW2 + vc];
                        }
                        v = ok ? v : 0.f;
                        const unsigned u = __builtin_bit_cast(unsigned, v);
                        bf[j] = (short)((u + 0x8000u) >> 16);   // fp32->bf16 round
                    }

                    const int Q = ccb * 18 + (dd * 3 + dd2) * 2 + ch16;
                    const short8 a = wpv[Q * 64 + lane];
                    acc = __builtin_amdgcn_mfma_f32_32x32x16_bf16(a, bf, acc, 0, 0, 0);
                }
            }
        }
    }

    // ---- in-block K-reduce, two-phase (r16 PASS idiom), 4 partials ----
    // C/D: col = lane&31, row b0 = (reg&3) + 8*(reg>>2) + 4*khalf (r12-proven)
    const int base = (wid & 1) * 1024;
    if (wid < 2) {
        #pragma unroll
        for (int i2 = 0; i2 < 16; ++i2) {
            const int b0 = (i2 & 3) + 8 * (i2 >> 2) + 4 * khalf;
            red[base + b0 * 32 + col] = acc[i2];
        }
    }
    __syncthreads();
    if (wid >= 2) {
        #pragma unroll
        for (int i2 = 0; i2 < 16; ++i2) {
            const int b0 = (i2 & 3) + 8 * (i2 >> 2) + 4 * khalf;
            red[base + b0 * 32 + col] += acc[i2];
        }
    }
    __syncthreads();

    float* on = out + (size_t)n * (BKT * HW2) + s0img;
    #pragma unroll
    for (int e = 0; e < 4; ++e) {
        const int elem = e * 256 + t;           // 0..1023 = b0*32 + c
        const float s = red[elem] + red[1024 + elem];
        on[(size_t)(elem >> 5) * HW2 + (elem & 31)] = s;
    }
}

// ---------------------------------------------------------------------------
extern "C" void kernel_launch(void* const* d_in, const int* in_sizes, int n_in,
                              void* d_out, int out_size, void* d_ws, size_t ws_size,
                              hipStream_t stream) {
    const float* x       = (const float*)d_in[0];
    const float* kernels = (const float*)d_in[1];
    const float* a       = (const float*)d_in[2];
    const int*   table   = (const int*)d_in[3];
    float* out = (float*)d_out;
    int*   rows = (int*)d_ws;
    unsigned short* wpack = (unsigned short*)((char*)d_ws + 512);

    hipLaunchKernelGGL(hash_rows_kernel, dim3(1), dim3(256), 0, stream,
                       x, a, table, rows);
    hipLaunchKernelGGL(build_wpack_kernel, dim3(288), dim3(256), 0, stream,
                       kernels, rows, wpack);
    hipLaunchKernelGGL(alsh_mfma_kernel, dim3(1568), dim3(256), 0, stream,
                       x, wpack, out);
}

// Round 21
// 61.710 us; speedup vs baseline: 2.0724x; 1.0700x over previous
//
#include <hip/hip_runtime.h>
#include <stdint.h>

#define C_IN 256
#define HW   56
#define HW2  3136          // 56*56
#define SPAN 2304          // 9*256
#define TS   16
#define BKT  32

typedef __attribute__((ext_vector_type(8)))  short short8;
typedef __attribute__((ext_vector_type(8)))  unsigned short ushort8;
typedef __attribute__((ext_vector_type(4)))  float f32x4;
typedef __attribute__((ext_vector_type(16))) float f32x16;
typedef float f32x4u __attribute__((ext_vector_type(4), aligned(4)));

// d_ws: [0,512) rows; [512, 147968) Wpack; [262144, +25690112) xT (NHWC bf16)
#define XT_OFF 262144
#define XT_BYTES (16u * HW2 * 256u * 2u)

// ---------------------------------------------------------------------------
// Kernel 1: hash -> 32 gathered row ids (byte-identical to all PASS rounds).
// ---------------------------------------------------------------------------
__global__ void hash_rows_kernel(const float* __restrict__ x,
                                 const float* __restrict__ a,
                                 const int*   __restrict__ table,
                                 int*         __restrict__ rows_out) {
    __shared__ float rd[256];
    __shared__ float rn[256];
    const int t = threadIdx.x;
    float dv = 0.f, nq = 0.f;
    for (int k = t; k < SPAN; k += 256) {
        const int p = k >> 8;
        const int c = k & 255;
        const int i = p / 3, j = p % 3;
        float v = 0.f;
        if (i >= 1 && j >= 1) v = x[c * HW2 + (i - 1) * HW + (j - 1)];
        dv += a[k] * v;
        nq += v * v;
    }
    rd[t] = dv; rn[t] = nq;
    __syncthreads();
    for (int s = 128; s > 0; s >>= 1) {
        if (t < s) { rd[t] += rd[t + s]; rn[t] += rn[t + s]; }
        __syncthreads();
    }
    if (t == 0) {
        const float nrm = sqrtf(rn[0]);
        const float sv  = rd[0] / nrm
                        + 0.5f * (a[SPAN] + a[SPAN+1] + a[SPAN+2] + a[SPAN+3] + a[SPAN+4]);
        const int idx = ((int)fabsf(floorf(sv))) % TS;
        #pragma unroll
        for (int b = 0; b < BKT; ++b) rows_out[b] = table[idx * BKT + b];
    }
}

// ---------------------------------------------------------------------------
// Kernel 2: build Wpack for 32x32x16 A-fragments (rounds 12-16 PASS).
// ---------------------------------------------------------------------------
__global__ void build_wpack_kernel(const float* __restrict__ kernels,
                                   const int*   __restrict__ rows,
                                   unsigned short* __restrict__ wp) {
    const int idx   = blockIdx.x * 256 + threadIdx.x;   // 0..73727
    const int j     = idx & 7;
    const int l     = (idx >> 3) & 63;
    const int Q     = idx >> 9;          // 0..143
    const int ccb   = Q / 18;
    const int rem   = Q % 18;
    const int p     = rem >> 1;
    const int ch16  = rem & 1;
    const int brow  = l & 31;
    const int khalf = l >> 5;
    const int k     = p * 256 + ccb * 32 + ch16 * 16 + khalf * 8 + j;
    const int row   = rows[brow];
    const float v = kernels[(size_t)row * SPAN + k] * 16.0f;
    unsigned u = __builtin_bit_cast(unsigned, v);
    u = (u + 0x7fffu + ((u >> 16) & 1u)) >> 16;       // RNE fp32->bf16
    wp[idx] = (unsigned short)u;
}

// ---------------------------------------------------------------------------
// Kernel T: NCHW fp32 -> NHWC bf16, curse-free:
//   read f32x4 coalesced; LDS = FLOAT array, scalar float writes + scalar
//   float reads (hash-proven type-consistent shape); pack in-register with
//   the GEMM's (u+0x8000)>>16 rounding; ushort8 coalesced global writes.
//   Tile: 32 pos x 256 ch; LDS 32x257 floats (pad -> <=2-way banks).
// ---------------------------------------------------------------------------
__global__ __launch_bounds__(256)
void transpose_kernel(const float* __restrict__ x,
                      unsigned short* __restrict__ xT) {
    __shared__ float tileF[32 * 257];           // 32896 B
    const int t  = threadIdx.x;
    const int n  = blockIdx.x / 98;             // 98 tiles of 32 pos per image
    const int p0 = (blockIdx.x % 98) * 32;
    const float* xn = x + (size_t)n * (C_IN * HW2);

    const int s4 = (t & 7) * 4;                 // position sub-base
    const int c0 = t >> 3;                      // 0..31
    #pragma unroll
    for (int iter = 0; iter < 8; ++iter) {
        const int ch = iter * 32 + c0;
        const f32x4 v = *(const f32x4*)(xn + (size_t)ch * HW2 + p0 + s4);
        #pragma unroll
        for (int j = 0; j < 4; ++j)
            tileF[(s4 + j) * 257 + ch] = v[j];  // float scalar write
    }
    __syncthreads();

    const int pos = t >> 3;                     // 0..31
    const int cq  = t & 7;
    unsigned short* dst = xT + ((size_t)n * HW2 + p0 + pos) * 256;
    #pragma unroll
    for (int iter = 0; iter < 4; ++iter) {
        const int ch = iter * 64 + cq * 8;
        ushort8 o;
        #pragma unroll
        for (int j = 0; j < 8; ++j) {           // float scalar reads
            const unsigned u = __builtin_bit_cast(unsigned, tileF[pos * 257 + ch + j]);
            o[j] = (unsigned short)((u + 0x8000u) >> 16);   // match GEMM rounding
        }
        *(ushort8*)(dst + ch) = o;              // 16B coalesced store
    }
}

// ---------------------------------------------------------------------------
// Kernel 3a: implicit-GEMM on NHWC-bf16 xT — r14 PASS chassis (512 thr,
// ccb = wid, in-block reduce, clean stores); B-frag = ONE short8 load
// (clamped addr + ok-select). Per wave-ccb: 36 VMEM vs r14's 66, zero pack
// VALU. bf16 values identical to r14 -> absmax unchanged.
// ---------------------------------------------------------------------------
__global__ __launch_bounds__(512, 4)
void alsh_mfma_xt_kernel(const unsigned short* __restrict__ xT,
                         const unsigned short* __restrict__ wp,
                         float* __restrict__ out) {
    __shared__ float red[8 * 1024];             // 32KB (r14-proven epilogue)

    const int b  = blockIdx.x;                  // 0..1567
    const int ct = (b & 7) * 196 + (b >> 3);    // XCD chunk swizzle (1568 = 8*196)

    const int t     = threadIdx.x;              // 0..511
    const int lane  = t & 63;
    const int wid   = t >> 6;                   // 0..7
    const int ccb   = wid;
    const int col   = lane & 31;
    const int khalf = lane >> 5;
    const int s0    = ct * 32;
    const int n     = s0 / HW2;
    const int s0img = s0 - n * HW2;
    const int sl    = s0img + col;
    const int h     = sl / HW;
    const int w     = sl - h * HW;
    const short8* xTn = (const short8*)(xT + (size_t)n * (HW2 * 256));
    const short8* wpv = (const short8*)wp;

    f32x16 acc = {0.f,0.f,0.f,0.f, 0.f,0.f,0.f,0.f, 0.f,0.f,0.f,0.f, 0.f,0.f,0.f,0.f};
    const short8 z8 = {0,0,0,0,0,0,0,0};
    const int ub = ccb * 4 + khalf;             // short8-unit base (+ch16*2)

    #pragma unroll
    for (int dd = 0; dd < 3; ++dd) {            // di = dd-1
        const int di     = dd - 1;
        const int rowpos = sl + di * HW;
        const int ih     = h + di;
        #pragma unroll
        for (int ch16 = 0; ch16 < 2; ++ch16) {
            #pragma unroll
            for (int dd2 = 0; dd2 < 3; ++dd2) { // dj = dd2-1
                const int dj = dd2 - 1;
                const int iw = w + dj;
                const bool ok = ((unsigned)ih < (unsigned)HW) & ((unsigned)iw < (unsigned)HW);
                const int voff = rowpos + dj;
                const int vc = voff < 0 ? 0 : (voff > HW2 - 1 ? HW2 - 1 : voff);

                short8 bv = xTn[(size_t)vc * 32 + ub + ch16 * 2];
                bv = ok ? bv : z8;

                const int Q = ccb * 18 + (dd * 3 + dd2) * 2 + ch16;
                const short8 a = wpv[Q * 64 + lane];
                acc = __builtin_amdgcn_mfma_f32_32x32x16_bf16(a, bv, acc, 0, 0, 0);
            }
        }
    }

    // ---- in-block K-reduce (r14 PASS epilogue, verbatim) ----
    const int base = wid * 1024;
    #pragma unroll
    for (int i2 = 0; i2 < 16; ++i2) {
        const int b0 = (i2 & 3) + 8 * (i2 >> 2) + 4 * khalf;
        red[base + b0 * 32 + col] = acc[i2];
    }
    __syncthreads();

    float* on = out + (size_t)n * (BKT * HW2) + s0img;
    #pragma unroll
    for (int e = 0; e < 2; ++e) {
        const int elem = e * 512 + t;
        float s = red[elem];
        #pragma unroll
        for (int w2 = 1; w2 < 8; ++w2) s += red[w2 * 1024 + elem];
        on[(size_t)(elem >> 5) * HW2 + (elem & 31)] = s;
    }
}

// ---------------------------------------------------------------------------
// Kernel 3b: r14 PASS kernel VERBATIM — ws_size fallback (no-regression floor).
// ---------------------------------------------------------------------------
__global__ __launch_bounds__(512, 4)
void alsh_mfma_reg_kernel(const float* __restrict__ x,
                          const unsigned short* __restrict__ wp,
                          float* __restrict__ out) {
    __shared__ float red[8 * 1024];
    const int b  = blockIdx.x;
    const int ct = (b & 7) * 196 + (b >> 3);
    const int t     = threadIdx.x;
    const int lane  = t & 63;
    const int wid   = t >> 6;
    const int ccb   = wid;
    const int col   = lane & 31;
    const int khalf = lane >> 5;
    const int s0    = ct * 32;
    const int n     = s0 / HW2;
    const int s0img = s0 - n * HW2;
    const int sl    = s0img + col;
    const int h     = sl / HW;
    const int w     = sl - h * HW;
    const float* xn = x + (size_t)n * (C_IN * HW2);
    const short8* wpv = (const short8*)wp;
    f32x16 acc = {0.f,0.f,0.f,0.f, 0.f,0.f,0.f,0.f, 0.f,0.f,0.f,0.f, 0.f,0.f,0.f,0.f};
    const int cc = ccb * 32;
    #pragma unroll
    for (int dd = 0; dd < 3; ++dd) {
        const int di     = dd - 1;
        const int rowpos = sl + di * HW;
        const int posm   = rowpos - 1;
        const int pc     = posm < 0 ? 0 : (posm > HW2 - 4 ? HW2 - 4 : posm);
        const bool shifted = (pc != posm);
        const int ih = h + di;
        #pragma unroll
        for (int ch16 = 0; ch16 < 2; ++ch16) {
            f32x4 V[8];
            #pragma unroll
            for (int j = 0; j < 8; ++j) {
                const int ch = cc + ch16 * 16 + khalf * 8 + j;
                V[j] = *(const f32x4u*)(xn + (size_t)ch * HW2 + pc);
            }
            #pragma unroll
            for (int dd2 = 0; dd2 < 3; ++dd2) {
                const int dj = dd2 - 1;
                const int iw = w + dj;
                const bool ok = ((unsigned)ih < (unsigned)HW) & ((unsigned)iw < (unsigned)HW);
                const int voff = rowpos + dj;
                short8 bf;
                #pragma unroll
                for (int j = 0; j < 8; ++j) {
                    float v = V[j][dd2];
                    if (shifted) {
                        const int vc = voff < 0 ? 0 : (voff > HW2 - 1 ? HW2 - 1 : voff);
                        v = xn[(size_t)(cc + ch16 * 16 + khalf * 8 + j) * HW2 + vc];
                    }
                    v = ok ? v : 0.f;
                    const unsigned u = __builtin_bit_cast(unsigned, v);
                    bf[j] = (short)((u + 0x8000u) >> 16);
                }
                const int Q = ccb * 18 + (dd * 3 + dd2) * 2 + ch16;
                const short8 a = wpv[Q * 64 + lane];
                acc = __builtin_amdgcn_mfma_f32_32x32x16_bf16(a, bf, acc, 0, 0, 0);
            }
        }
    }
    const int base = wid * 1024;
    #pragma unroll
    for (int i2 = 0; i2 < 16; ++i2) {
        const int b0 = (i2 & 3) + 8 * (i2 >> 2) + 4 * khalf;
        red[base + b0 * 32 + col] = acc[i2];
    }
    __syncthreads();
    float* on = out + (size_t)n * (BKT * HW2) + s0img;
    #pragma unroll
    for (int e = 0; e < 2; ++e) {
        const int elem = e * 512 + t;
        float s = red[elem];
        #pragma unroll
        for (int w2 = 1; w2 < 8; ++w2) s += red[w2 * 1024 + elem];
        on[(size_t)(elem >> 5) * HW2 + (elem & 31)] = s;
    }
}

// ---------------------------------------------------------------------------
extern "C" void kernel_launch(void* const* d_in, const int* in_sizes, int n_in,
                              void* d_out, int out_size, void* d_ws, size_t ws_size,
                              hipStream_t stream) {
    const float* x       = (const float*)d_in[0];
    const float* kernels = (const float*)d_in[1];
    const float* a       = (const float*)d_in[2];
    const int*   table   = (const int*)d_in[3];
    float* out = (float*)d_out;
    int*            rows  = (int*)d_ws;
    unsigned short* wpack = (unsigned short*)((char*)d_ws + 512);

    hipLaunchKernelGGL(hash_rows_kernel, dim3(1), dim3(256), 0, stream,
                       x, a, table, rows);
    hipLaunchKernelGGL(build_wpack_kernel, dim3(288), dim3(256), 0, stream,
                       kernels, rows, wpack);

    if (ws_size >= (size_t)XT_OFF + XT_BYTES) {
        unsigned short* xT = (unsigned short*)((char*)d_ws + XT_OFF);
        hipLaunchKernelGGL(transpose_kernel, dim3(1568), dim3(256), 0, stream,
                           x, xT);
        hipLaunchKernelGGL(alsh_mfma_xt_kernel, dim3(1568), dim3(512), 0, stream,
                           xT, wpack, out);
    } else {
        hipLaunchKernelGGL(alsh_mfma_reg_kernel, dim3(1568), dim3(512), 0, stream,
                           x, wpack, out);
    }
}

// Round 22
// 50.113 us; speedup vs baseline: 2.5520x; 1.2314x over previous
//
#include <hip/hip_runtime.h>
#include <stdint.h>

#define C_IN 256
#define HW   56
#define HW2  3136          // 56*56
#define SPAN 2304          // 9*256
#define TS   16
#define BKT  32

typedef __attribute__((ext_vector_type(8)))  short short8;
typedef __attribute__((ext_vector_type(8)))  unsigned short ushort8;
typedef __attribute__((ext_vector_type(4)))  float f32x4;
typedef __attribute__((ext_vector_type(16))) float f32x16;
typedef float f32x4u __attribute__((ext_vector_type(4), aligned(4)));

// d_ws: [0,512) rows; [512, 147968) Wpack; [262144, +25690112) xT
// xT layout (short8 units): unit(n, cb, pos) = n*32*HW2 + cb*HW2 + pos
//   holding channels cb*8..cb*8+7 (bf16) at spatial pos.
#define XT_OFF 262144
#define XT_BYTES (16u * HW2 * 256u * 2u)

// ---------------------------------------------------------------------------
// Kernel 1: hash -> 32 gathered row ids (byte-identical to all PASS rounds).
// ---------------------------------------------------------------------------
__global__ void hash_rows_kernel(const float* __restrict__ x,
                                 const float* __restrict__ a,
                                 const int*   __restrict__ table,
                                 int*         __restrict__ rows_out) {
    __shared__ float rd[256];
    __shared__ float rn[256];
    const int t = threadIdx.x;
    float dv = 0.f, nq = 0.f;
    for (int k = t; k < SPAN; k += 256) {
        const int p = k >> 8;
        const int c = k & 255;
        const int i = p / 3, j = p % 3;
        float v = 0.f;
        if (i >= 1 && j >= 1) v = x[c * HW2 + (i - 1) * HW + (j - 1)];
        dv += a[k] * v;
        nq += v * v;
    }
    rd[t] = dv; rn[t] = nq;
    __syncthreads();
    for (int s = 128; s > 0; s >>= 1) {
        if (t < s) { rd[t] += rd[t + s]; rn[t] += rn[t + s]; }
        __syncthreads();
    }
    if (t == 0) {
        const float nrm = sqrtf(rn[0]);
        const float sv  = rd[0] / nrm
                        + 0.5f * (a[SPAN] + a[SPAN+1] + a[SPAN+2] + a[SPAN+3] + a[SPAN+4]);
        const int idx = ((int)fabsf(floorf(sv))) % TS;
        #pragma unroll
        for (int b = 0; b < BKT; ++b) rows_out[b] = table[idx * BKT + b];
    }
}

// ---------------------------------------------------------------------------
// Kernel 2: build Wpack for 32x32x16 A-fragments (rounds 12-21 PASS).
// ---------------------------------------------------------------------------
__global__ void build_wpack_kernel(const float* __restrict__ kernels,
                                   const int*   __restrict__ rows,
                                   unsigned short* __restrict__ wp) {
    const int idx   = blockIdx.x * 256 + threadIdx.x;   // 0..73727
    const int j     = idx & 7;
    const int l     = (idx >> 3) & 63;
    const int Q     = idx >> 9;          // 0..143
    const int ccb   = Q / 18;
    const int rem   = Q % 18;
    const int p     = rem >> 1;
    const int ch16  = rem & 1;
    const int brow  = l & 31;
    const int khalf = l >> 5;
    const int k     = p * 256 + ccb * 32 + ch16 * 16 + khalf * 8 + j;
    const int row   = rows[brow];
    const float v = kernels[(size_t)row * SPAN + k] * 16.0f;
    unsigned u = __builtin_bit_cast(unsigned, v);
    u = (u + 0x7fffu + ((u >> 16) & 1u)) >> 16;       // RNE fp32->bf16
    wp[idx] = (unsigned short)u;
}

// ---------------------------------------------------------------------------
// Kernel T: NCHW fp32 -> channel-blocked bf16 (r21 PASS structure; only the
// output address changed to the [cb][pos][8] layout).
// LDS = FLOAT array, scalar float writes/reads (type-consistent, proven).
// ---------------------------------------------------------------------------
__global__ __launch_bounds__(256)
void transpose_kernel(const float* __restrict__ x,
                      unsigned short* __restrict__ xT) {
    __shared__ float tileF[32 * 257];           // 32896 B
    const int t  = threadIdx.x;
    const int n  = blockIdx.x / 98;             // 98 tiles of 32 pos per image
    const int p0 = (blockIdx.x % 98) * 32;
    const float* xn = x + (size_t)n * (C_IN * HW2);

    const int s4 = (t & 7) * 4;                 // position sub-base
    const int c0 = t >> 3;                      // 0..31
    #pragma unroll
    for (int iter = 0; iter < 8; ++iter) {
        const int ch = iter * 32 + c0;
        const f32x4 v = *(const f32x4*)(xn + (size_t)ch * HW2 + p0 + s4);
        #pragma unroll
        for (int j = 0; j < 4; ++j)
            tileF[(s4 + j) * 257 + ch] = v[j];  // float scalar write
    }
    __syncthreads();

    const int pos = t >> 3;                     // 0..31
    const int cq  = t & 7;
    const size_t nbase = (size_t)n * 32 * HW2;  // short8-unit base
    #pragma unroll
    for (int iter = 0; iter < 4; ++iter) {
        const int ch = iter * 64 + cq * 8;
        const int cb = ch >> 3;                 // iter*8 + cq
        ushort8 o;
        #pragma unroll
        for (int j = 0; j < 8; ++j) {           // float scalar reads
            const unsigned u = __builtin_bit_cast(unsigned, tileF[pos * 257 + ch + j]);
            o[j] = (unsigned short)((u + 0x8000u) >> 16);   // match GEMM rounding
        }
        *(ushort8*)(xT + (nbase + (size_t)cb * HW2 + p0 + pos) * 8) = o;
    }
}

// ---------------------------------------------------------------------------
// Kernel 3a: implicit-GEMM on channel-blocked bf16 xT.
//   256 threads = 4 waves, one 32-col tile, wave runs 2 ccb (r19/r20-proven
//   order); B-frag = ONE short8 load, COALESCED (lane's unit = cb*HW2+vc,
//   32 consecutive units per half-wave). Light body (~45 VGPR, no fp32
//   windows) -> launch_bounds(256,8) safe -> 8 blocks/CU -> grid 1568 =
//   6.125 blocks/CU resident in ONE generation.
//   Reduce: two-phase 4-partial (r19/r20 PASS idiom), 8KB LDS.
// ---------------------------------------------------------------------------
__global__ __launch_bounds__(256, 8)
void alsh_mfma_xtb_kernel(const unsigned short* __restrict__ xT,
                          const unsigned short* __restrict__ wp,
                          float* __restrict__ out) {
    __shared__ float red[2 * 1024];             // 8KB

    const int b  = blockIdx.x;                  // 0..1567
    const int ct = (b & 7) * 196 + (b >> 3);    // XCD chunk swizzle (1568 = 8*196)

    const int t     = threadIdx.x;              // 0..255
    const int lane  = t & 63;
    const int wid   = t >> 6;                   // 0..3
    const int col   = lane & 31;
    const int khalf = lane >> 5;
    const int s0    = ct * 32;
    const int n     = s0 / HW2;
    const int s0img = s0 - n * HW2;
    const int sl    = s0img + col;
    const int h     = sl / HW;
    const int w     = sl - h * HW;
    const short8* xTn = (const short8*)xT + (size_t)n * (32 * HW2);
    const short8* wpv = (const short8*)wp;

    f32x16 acc = {0.f,0.f,0.f,0.f, 0.f,0.f,0.f,0.f, 0.f,0.f,0.f,0.f, 0.f,0.f,0.f,0.f};
    const short8 z8 = {0,0,0,0,0,0,0,0};

    #pragma unroll
    for (int cq = 0; cq < 2; ++cq) {            // 2 ccb per wave (r19/r20 order)
        const int ccb = wid * 2 + cq;
        #pragma unroll
        for (int dd = 0; dd < 3; ++dd) {        // di = dd-1
            const int di     = dd - 1;
            const int rowpos = sl + di * HW;
            const int ih     = h + di;
            #pragma unroll
            for (int ch16 = 0; ch16 < 2; ++ch16) {
                const int cb = ccb * 4 + ch16 * 2 + khalf;   // channel block
                #pragma unroll
                for (int dd2 = 0; dd2 < 3; ++dd2) {          // dj = dd2-1
                    const int dj = dd2 - 1;
                    const int iw = w + dj;
                    const bool ok = ((unsigned)ih < (unsigned)HW) & ((unsigned)iw < (unsigned)HW);
                    const int voff = rowpos + dj;
                    const int vc = voff < 0 ? 0 : (voff > HW2 - 1 ? HW2 - 1 : voff);

                    short8 bv = xTn[(size_t)cb * HW2 + vc];  // coalesced 16B
                    bv = ok ? bv : z8;

                    const int Q = ccb * 18 + (dd * 3 + dd2) * 2 + ch16;
                    const short8 a = wpv[Q * 64 + lane];
                    acc = __builtin_amdgcn_mfma_f32_32x32x16_bf16(a, bv, acc, 0, 0, 0);
                }
            }
        }
    }

    // ---- in-block K-reduce, two-phase (r19/r20 PASS idiom), 4 partials ----
    const int base = (wid & 1) * 1024;
    if (wid < 2) {
        #pragma unroll
        for (int i2 = 0; i2 < 16; ++i2) {
            const int b0 = (i2 & 3) + 8 * (i2 >> 2) + 4 * khalf;
            red[base + b0 * 32 + col] = acc[i2];
        }
    }
    __syncthreads();
    if (wid >= 2) {
        #pragma unroll
        for (int i2 = 0; i2 < 16; ++i2) {
            const int b0 = (i2 & 3) + 8 * (i2 >> 2) + 4 * khalf;
            red[base + b0 * 32 + col] += acc[i2];
        }
    }
    __syncthreads();

    float* on = out + (size_t)n * (BKT * HW2) + s0img;
    #pragma unroll
    for (int e = 0; e < 4; ++e) {
        const int elem = e * 256 + t;           // 0..1023 = b0*32 + c
        const float s = red[elem] + red[1024 + elem];
        on[(size_t)(elem >> 5) * HW2 + (elem & 31)] = s;
    }
}

// ---------------------------------------------------------------------------
// Kernel 3b: r14 PASS kernel VERBATIM — ws_size fallback (no-regression floor).
// ---------------------------------------------------------------------------
__global__ __launch_bounds__(512, 4)
void alsh_mfma_reg_kernel(const float* __restrict__ x,
                          const unsigned short* __restrict__ wp,
                          float* __restrict__ out) {
    __shared__ float red[8 * 1024];
    const int b  = blockIdx.x;
    const int ct = (b & 7) * 196 + (b >> 3);
    const int t     = threadIdx.x;
    const int lane  = t & 63;
    const int wid   = t >> 6;
    const int ccb   = wid;
    const int col   = lane & 31;
    const int khalf = lane >> 5;
    const int s0    = ct * 32;
    const int n     = s0 / HW2;
    const int s0img = s0 - n * HW2;
    const int sl    = s0img + col;
    const int h     = sl / HW;
    const int w     = sl - h * HW;
    const float* xn = x + (size_t)n * (C_IN * HW2);
    const short8* wpv = (const short8*)wp;
    f32x16 acc = {0.f,0.f,0.f,0.f, 0.f,0.f,0.f,0.f, 0.f,0.f,0.f,0.f, 0.f,0.f,0.f,0.f};
    const int cc = ccb * 32;
    #pragma unroll
    for (int dd = 0; dd < 3; ++dd) {
        const int di     = dd - 1;
        const int rowpos = sl + di * HW;
        const int posm   = rowpos - 1;
        const int pc     = posm < 0 ? 0 : (posm > HW2 - 4 ? HW2 - 4 : posm);
        const bool shifted = (pc != posm);
        const int ih = h + di;
        #pragma unroll
        for (int ch16 = 0; ch16 < 2; ++ch16) {
            f32x4 V[8];
            #pragma unroll
            for (int j = 0; j < 8; ++j) {
                const int ch = cc + ch16 * 16 + khalf * 8 + j;
                V[j] = *(const f32x4u*)(xn + (size_t)ch * HW2 + pc);
            }
            #pragma unroll
            for (int dd2 = 0; dd2 < 3; ++dd2) {
                const int dj = dd2 - 1;
                const int iw = w + dj;
                const bool ok = ((unsigned)ih < (unsigned)HW) & ((unsigned)iw < (unsigned)HW);
                const int voff = rowpos + dj;
                short8 bf;
                #pragma unroll
                for (int j = 0; j < 8; ++j) {
                    float v = V[j][dd2];
                    if (shifted) {
                        const int vc = voff < 0 ? 0 : (voff > HW2 - 1 ? HW2 - 1 : voff);
                        v = xn[(size_t)(cc + ch16 * 16 + khalf * 8 + j) * HW2 + vc];
                    }
                    v = ok ? v : 0.f;
                    const unsigned u = __builtin_bit_cast(unsigned, v);
                    bf[j] = (short)((u + 0x8000u) >> 16);
                }
                const int Q = ccb * 18 + (dd * 3 + dd2) * 2 + ch16;
                const short8 a = wpv[Q * 64 + lane];
                acc = __builtin_amdgcn_mfma_f32_32x32x16_bf16(a, bf, acc, 0, 0, 0);
            }
        }
    }
    const int base = wid * 1024;
    #pragma unroll
    for (int i2 = 0; i2 < 16; ++i2) {
        const int b0 = (i2 & 3) + 8 * (i2 >> 2) + 4 * khalf;
        red[base + b0 * 32 + col] = acc[i2];
    }
    __syncthreads();
    float* on = out + (size_t)n * (BKT * HW2) + s0img;
    #pragma unroll
    for (int e = 0; e < 2; ++e) {
        const int elem = e * 512 + t;
        float s = red[elem];
        #pragma unroll
        for (int w2 = 1; w2 < 8; ++w2) s += red[w2 * 1024 + elem];
        on[(size_t)(elem >> 5) * HW2 + (elem & 31)] = s;
    }
}

// ---------------------------------------------------------------------------
extern "C" void kernel_launch(void* const* d_in, const int* in_sizes, int n_in,
                              void* d_out, int out_size, void* d_ws, size_t ws_size,
                              hipStream_t stream) {
    const float* x       = (const float*)d_in[0];
    const float* kernels = (const float*)d_in[1];
    const float* a       = (const float*)d_in[2];
    const int*   table   = (const int*)d_in[3];
    float* out = (float*)d_out;
    int*            rows  = (int*)d_ws;
    unsigned short* wpack = (unsigned short*)((char*)d_ws + 512);

    hipLaunchKernelGGL(hash_rows_kernel, dim3(1), dim3(256), 0, stream,
                       x, a, table, rows);
    hipLaunchKernelGGL(build_wpack_kernel, dim3(288), dim3(256), 0, stream,
                       kernels, rows, wpack);

    if (ws_size >= (size_t)XT_OFF + XT_BYTES) {
        unsigned short* xT = (unsigned short*)((char*)d_ws + XT_OFF);
        hipLaunchKernelGGL(transpose_kernel, dim3(1568), dim3(256), 0, stream,
                           x, xT);
        hipLaunchKernelGGL(alsh_mfma_xtb_kernel, dim3(1568), dim3(256), 0, stream,
                           xT, wpack, out);
    } else {
        hipLaunchKernelGGL(alsh_mfma_reg_kernel, dim3(1568), dim3(512), 0, stream,
                           x, wpack, out);
    }
}